// Round 8
// baseline (2237.108 us; speedup 1.0000x reference)
//
#include <hip/hip_runtime.h>
#include <type_traits>

typedef _Float16 f16;
typedef _Float16 f16x4 __attribute__((ext_vector_type(4)));
typedef _Float16 f16x8 __attribute__((ext_vector_type(8)));
typedef float    f32x4 __attribute__((ext_vector_type(4)));

constexpr int TT = 512;   // timesteps
constexpr int FF = 64;    // input features
constexpr int H1 = 128;   // layer-1 hidden (512 gate cols)
constexpr int H2 = 64;    // layer-2 hidden (256 gate cols)
constexpr int D1 = 25;    // dense-1 width
constexpr int S1 = 136;   // h1 LDS row stride (f16): b128 reads land 2-way (free)
constexpr int S2 = 72;    // h2 LDS row stride
constexpr int XC = 8;     // x timesteps per staged LDS chunk (16 KB/buffer)
constexpr float L2E = 1.44269504088896f;

// z pre-scaled by log2(e) at weight-load time: sigmoid = rcp(1 + 2^-z).
__device__ __forceinline__ float sigm2(float z) {
    return __builtin_amdgcn_rcpf(1.f + __builtin_amdgcn_exp2f(-z));
}

__device__ __forceinline__ f32x4 mfma16(f16x8 a, f16x8 b, f32x4 c) {
    return __builtin_amdgcn_mfma_f32_16x16x32_f16(a, b, c, 0, 0, 0);
}

__device__ __forceinline__ void gl_lds16(const f16* g, f16* l) {
    __builtin_amdgcn_global_load_lds(
        (const __attribute__((address_space(1))) unsigned int*)g,
        (__attribute__((address_space(3))) unsigned int*)l, 16, 0, 0);
}

// pre-pass: x fp32 -> f16 so staging is a raw byte copy.
__global__ void cvt_x_kernel(const float* __restrict__ x, f16* __restrict__ xh) {
    const size_t i = ((size_t)blockIdx.x * blockDim.x + threadIdx.x) * 4;
    const float4 v = *(const float4*)(x + i);
    f16x4 h; h[0] = (f16)v.x; h[1] = (f16)v.y; h[2] = (f16)v.z; h[3] = (f16)v.w;
    *(f16x4*)(xh + i) = h;
}

// 32 blocks x 512 threads (8 waves, 2/SIMD => 256-VGPR budget).
// Waves 4-7: layer-1 step i, 8 N-tiles each as two gate-complete 4-tile passes
//   sharing ONE set of A-fragment reads (halves the per-CU LDS read burst).
// Waves 0-3: layer-2 step i-1 (4 N-tiles) + x chunk staging.
// Ping-pong h1/h2 LDS buffers => ONE barrier/step; compile-time parity.
__global__ __launch_bounds__(512, 2)
void lstm_pipe6(const f16* __restrict__ xh, const float* __restrict__ W1,
                const float* __restrict__ U1, const float* __restrict__ b1,
                const float* __restrict__ W2, const float* __restrict__ U2,
                const float* __restrict__ b2, const float* __restrict__ Wd1,
                const float* __restrict__ bd1,const float* __restrict__ Wd2,
                const float* __restrict__ bd2, float* __restrict__ out)
{
    const int tid  = threadIdx.x;
    const int w    = tid >> 6;      // wave 0..7
    const int lane = tid & 63;
    const int quad = lane >> 4;     // 0..3
    const int lid  = lane & 15;     // 0..15
    const int b0   = blockIdx.x * 16;
    const bool isL1 = (w >= 4);
    const int  w1   = w - 4;        // L1 wave index 0..3
    const int  w2   = w;            // L2 wave index 0..3

    __shared__ __align__(16) f16 h1b[2][16][S1];
    __shared__ __align__(16) f16 h2b[2][16][S2];
    // x chunk layout: [tl(8)][fseg(8)][row(16)] of 8-f16 (16 B) segments.
    __shared__ __align__(16) f16 xlds[2][XC * 8 * 16 * 8];
    __shared__ float h2f[16][H2];
    __shared__ float dsh[16][D1];

    for (int i = tid; i < 2 * 16 * S1 / 2; i += 512) ((unsigned*)h1b)[i] = 0u;
    for (int i = tid; i < 2 * 16 * S2 / 2; i += 512) ((unsigned*)h2b)[i] = 0u;

    // stage x chunk 0 (timesteps 0..7): waves 0-3 (tid<256), 4 iters
    if (tid < 256) {
        for (int s = tid; s < XC * 8 * 16; s += 256) {
            const int tl = s >> 7, fs = (s >> 4) & 7, row = s & 15;
            const f16* gp = xh + ((size_t)(b0 + row) * TT + tl) * FF + fs * 8;
            gl_lds16(gp, &xlds[0][(s >> 6) * 512]);
        }
    }

    // ---- weight fragments, B-layout n=lid, k=quad*8+e; i/f/o pre-scaled by log2e ----
    // L1 waves: wt1[h][g][c]: n = 128g + 32*w1 + 16h + lid.
    //           c=0..3: U1 (k=32c+...), c=4..5: W1 (k=32(c-4)+...)   (192 VGPRs)
    // L2 waves: wt2[g][c]: n = 64g + 16*w2 + lid. c=0..3: W2, c=4..5: U2 (96 VGPRs)
    f16x8 wt1[2][4][6];
    f16x8 wt2[4][6];
    float bias1[2][4], bias2[4];
    float cs1[8] = {0,0,0,0,0,0,0,0};
    float cs2[4] = {0,0,0,0};

    if (isL1) {
#pragma unroll
        for (int h = 0; h < 2; ++h) {
#pragma unroll
            for (int g = 0; g < 4; ++g) {
                const float sc = (g == 2) ? 1.f : L2E;
                const int n = 128 * g + 32 * w1 + 16 * h + lid;
                bias1[h][g] = b1[n] * sc;
#pragma unroll
                for (int c = 0; c < 4; ++c) {
                    f16x8 f;
#pragma unroll
                    for (int e = 0; e < 8; ++e)
                        f[e] = (f16)(U1[(32 * c + quad * 8 + e) * 512 + n] * sc);
                    wt1[h][g][c] = f;
                }
#pragma unroll
                for (int c = 0; c < 2; ++c) {
                    f16x8 f;
#pragma unroll
                    for (int e = 0; e < 8; ++e)
                        f[e] = (f16)(W1[(32 * c + quad * 8 + e) * 512 + n] * sc);
                    wt1[h][g][4 + c] = f;
                }
            }
        }
    } else {
#pragma unroll
        for (int g = 0; g < 4; ++g) {
            const float sc = (g == 2) ? 1.f : L2E;
            const int n = 64 * g + 16 * w2 + lid;
            bias2[g] = b2[n] * sc;
#pragma unroll
            for (int c = 0; c < 4; ++c) {
                f16x8 f;
#pragma unroll
                for (int e = 0; e < 8; ++e)
                    f[e] = (f16)(W2[(32 * c + quad * 8 + e) * 256 + n] * sc);
                wt2[g][c] = f;
            }
#pragma unroll
            for (int c = 0; c < 2; ++c) {
                f16x8 f;
#pragma unroll
                for (int e = 0; e < 8; ++e)
                    f[e] = (f16)(U2[(32 * c + quad * 8 + e) * 256 + n] * sc);
                wt2[g][4 + c] = f;
            }
        }
    }
    __syncthreads();   // also drains staging vmcnt

    // one pipeline step; PAR = i&1 at compile time => LDS offsets are immediates
    auto step = [&](auto parc, int i) {
        constexpr int PAR = decltype(parc)::value;
        constexpr int PR = PAR ^ 1;   // h1[i-1]
        constexpr int PW = PAR;       // h1[i]
        constexpr int QR = PAR;       // h2[i-2]
        constexpr int QW = PAR ^ 1;   // h2[i-1]
        if (isL1) {
            const f16* xc = &xlds[(i >> 3) & 1][(i & 7) * 1024];
            f16x8 fr0 = *(const f16x8*)&h1b[PR][lid][quad * 8];
            f16x8 fr1 = *(const f16x8*)&h1b[PR][lid][32 + quad * 8];
            f16x8 fr2 = *(const f16x8*)&h1b[PR][lid][64 + quad * 8];
            f16x8 fr3 = *(const f16x8*)&h1b[PR][lid][96 + quad * 8];
            f16x8 xf0 = *(const f16x8*)&xc[(quad * 16 + lid) * 8];
            f16x8 xf1 = *(const f16x8*)&xc[((4 + quad) * 16 + lid) * 8];
#pragma unroll
            for (int h = 0; h < 2; ++h) {       // two gate-complete 4-tile passes
                f32x4 acc[4];
#pragma unroll
                for (int g = 0; g < 4; ++g) {
                    f32x4 a = {0.f, 0.f, 0.f, 0.f};
                    a = mfma16(fr0, wt1[h][g][0], a);
                    a = mfma16(fr1, wt1[h][g][1], a);
                    a = mfma16(fr2, wt1[h][g][2], a);
                    a = mfma16(fr3, wt1[h][g][3], a);
                    a = mfma16(xf0, wt1[h][g][4], a);
                    a = mfma16(xf1, wt1[h][g][5], a);
                    acc[g] = a;
                }
#pragma unroll
                for (int r = 0; r < 4; ++r) {
                    const float ig = sigm2(acc[0][r] + bias1[h][0]);
                    const float fg = sigm2(acc[1][r] + bias1[h][1]);
                    const float gg = fmaxf(acc[2][r] + bias1[h][2], 0.f);
                    const float og = sigm2(acc[3][r] + bias1[h][3]);
                    const float cc = fg * cs1[h * 4 + r] + ig * gg;
                    cs1[h * 4 + r] = cc;
                    const float hv = og * fmaxf(cc, 0.f);
                    h1b[PW][quad * 4 + r][32 * w1 + 16 * h + lid] = (f16)hv;
                }
            }
        } else {
            if (i >= 1) {
                f16x8 fr0 = *(const f16x8*)&h1b[PR][lid][quad * 8];
                f16x8 fr1 = *(const f16x8*)&h1b[PR][lid][32 + quad * 8];
                f16x8 fr2 = *(const f16x8*)&h1b[PR][lid][64 + quad * 8];
                f16x8 fr3 = *(const f16x8*)&h1b[PR][lid][96 + quad * 8];
                f16x8 fr4 = *(const f16x8*)&h2b[QR][lid][quad * 8];
                f16x8 fr5 = *(const f16x8*)&h2b[QR][lid][32 + quad * 8];
                f32x4 acc[4];
#pragma unroll
                for (int g = 0; g < 4; ++g) {
                    f32x4 a = {0.f, 0.f, 0.f, 0.f};
                    a = mfma16(fr0, wt2[g][0], a);
                    a = mfma16(fr1, wt2[g][1], a);
                    a = mfma16(fr2, wt2[g][2], a);
                    a = mfma16(fr3, wt2[g][3], a);
                    a = mfma16(fr4, wt2[g][4], a);
                    a = mfma16(fr5, wt2[g][5], a);
                    acc[g] = a;
                }
#pragma unroll
                for (int r = 0; r < 4; ++r) {
                    const float ig = sigm2(acc[0][r] + bias2[0]);
                    const float fg = sigm2(acc[1][r] + bias2[1]);
                    const float gg = fmaxf(acc[2][r] + bias2[2], 0.f);
                    const float og = sigm2(acc[3][r] + bias2[3]);
                    const float cc = fg * cs2[r] + ig * gg;
                    cs2[r] = cc;
                    const float hv = og * fmaxf(cc, 0.f);
                    h2b[QW][quad * 4 + r][16 * w2 + lid] = (f16)hv;
                }
            }
        }
    };

    // ---------------- main loop, unrolled x2: ONE barrier per step ----------------
    for (int ii = 0; ii < TT; ii += 2) {
        // stage next x chunk (L2 waves; drains at this step's barrier)
        if ((ii & (XC - 1)) == 0 && ii + XC < TT && tid < 256) {
            const int nc = (ii >> 3) + 1;
            f16* dst = xlds[nc & 1];
            for (int s = tid; s < XC * 8 * 16; s += 256) {
                const int tl = s >> 7, fs = (s >> 4) & 7, row = s & 15;
                const f16* gp = xh + ((size_t)(b0 + row) * TT + (nc * XC + tl)) * FF + fs * 8;
                gl_lds16(gp, &dst[(s >> 6) * 512]);
            }
        }
        step(std::integral_constant<int, 0>{}, ii);
        __syncthreads();
        step(std::integral_constant<int, 1>{}, ii + 1);
        __syncthreads();
    }

    // final pipeline step i=TT (even parity): L2 consumes h1[TT-1], exports h2 f32
    if (!isL1) {
        f16x8 fr0 = *(const f16x8*)&h1b[1][lid][quad * 8];
        f16x8 fr1 = *(const f16x8*)&h1b[1][lid][32 + quad * 8];
        f16x8 fr2 = *(const f16x8*)&h1b[1][lid][64 + quad * 8];
        f16x8 fr3 = *(const f16x8*)&h1b[1][lid][96 + quad * 8];
        f16x8 fr4 = *(const f16x8*)&h2b[0][lid][quad * 8];
        f16x8 fr5 = *(const f16x8*)&h2b[0][lid][32 + quad * 8];
        f32x4 acc[4];
#pragma unroll
        for (int g = 0; g < 4; ++g) {
            f32x4 a = {0.f, 0.f, 0.f, 0.f};
            a = mfma16(fr0, wt2[g][0], a);
            a = mfma16(fr1, wt2[g][1], a);
            a = mfma16(fr2, wt2[g][2], a);
            a = mfma16(fr3, wt2[g][3], a);
            a = mfma16(fr4, wt2[g][4], a);
            a = mfma16(fr5, wt2[g][5], a);
            acc[g] = a;
        }
#pragma unroll
        for (int r = 0; r < 4; ++r) {
            const float ig = sigm2(acc[0][r] + bias2[0]);
            const float fg = sigm2(acc[1][r] + bias2[1]);
            const float gg = fmaxf(acc[2][r] + bias2[2], 0.f);
            const float og = sigm2(acc[3][r] + bias2[3]);
            const float cc = fg * cs2[r] + ig * gg;
            const float hv = og * fmaxf(cc, 0.f);
            h2f[quad * 4 + r][16 * w2 + lid] = hv;
        }
    }
    __syncthreads();

    // ---------------- dense head ----------------
    for (int idx = tid; idx < 16 * D1; idx += 512) {
        const int bq = idx / D1, p = idx % D1;
        float d = bd1[p];
#pragma unroll
        for (int k = 0; k < H2; ++k) d += h2f[bq][k] * Wd1[k * D1 + p];
        dsh[bq][p] = d * Wd2[p];
    }
    __syncthreads();
    if (tid < 16) {
        float o = bd2[0];
#pragma unroll
        for (int p = 0; p < D1; ++p) o += dsh[tid][p];
        out[b0 + tid] = o;
    }
}

extern "C" void kernel_launch(void* const* d_in, const int* in_sizes, int n_in,
                              void* d_out, int out_size, void* d_ws, size_t ws_size,
                              hipStream_t stream) {
    (void)in_sizes; (void)n_in; (void)out_size; (void)ws_size;
    const float* x   = (const float*)d_in[0];
    const float* W1  = (const float*)d_in[1];
    const float* U1  = (const float*)d_in[2];
    const float* b1  = (const float*)d_in[3];
    const float* W2  = (const float*)d_in[4];
    const float* U2  = (const float*)d_in[5];
    const float* b2  = (const float*)d_in[6];
    const float* Wd1 = (const float*)d_in[7];
    const float* bd1 = (const float*)d_in[8];
    const float* Wd2 = (const float*)d_in[9];
    const float* bd2 = (const float*)d_in[10];
    float* out = (float*)d_out;
    f16*   xh  = (f16*)d_ws;    // 512*512*64 f16 = 32 MiB scratch

    const int nx = 512 * 512 * 64;
    cvt_x_kernel<<<dim3(nx / (256 * 4)), dim3(256), 0, stream>>>(x, xh);
    lstm_pipe6<<<dim3(32), dim3(512), 0, stream>>>(
        xh, W1, U1, b1, W2, U2, b2, Wd1, bd1, Wd2, bd2, out);
}

// Round 11
// 714.163 us; speedup vs baseline: 3.1325x; 3.1325x over previous
//
#include <hip/hip_runtime.h>
#include <type_traits>

typedef _Float16 f16;
typedef _Float16 f16x4 __attribute__((ext_vector_type(4)));
typedef _Float16 f16x8 __attribute__((ext_vector_type(8)));
typedef float    f32x4 __attribute__((ext_vector_type(4)));

constexpr int TT = 512;   // timesteps
constexpr int FF = 64;    // input features
constexpr int H1 = 128;   // layer-1 hidden (512 gate cols)
constexpr int H2 = 64;    // layer-2 hidden (256 gate cols)
constexpr int D1 = 25;    // dense-1 width
constexpr int S1 = 136;   // h1 LDS row stride (f16)
constexpr int S2 = 72;    // h2 LDS row stride
constexpr int XC = 8;     // x timesteps per staged LDS chunk
constexpr float L2E = 1.44269504088896f;

// z pre-scaled by log2(e) at weight-load time: sigmoid = rcp(1 + 2^-z).
__device__ __forceinline__ float sigm2(float z) {
    return __builtin_amdgcn_rcpf(1.f + __builtin_amdgcn_exp2f(-z));
}

__device__ __forceinline__ f32x4 mfma16(f16x8 a, f16x8 b, f32x4 c) {
    return __builtin_amdgcn_mfma_f32_16x16x32_f16(a, b, c, 0, 0, 0);
}

__device__ __forceinline__ void gl_lds16(const f16* g, f16* l) {
    __builtin_amdgcn_global_load_lds(
        (const __attribute__((address_space(1))) unsigned int*)g,
        (__attribute__((address_space(3))) unsigned int*)l, 16, 0, 0);
}

// pre-pass: x fp32 -> f16 so staging is a raw byte copy.
__global__ void cvt_x_kernel(const float* __restrict__ x, f16* __restrict__ xh) {
    const size_t i = ((size_t)blockIdx.x * blockDim.x + threadIdx.x) * 4;
    const float4 v = *(const float4*)(x + i);
    f16x4 h; h[0] = (f16)v.x; h[1] = (f16)v.y; h[2] = (f16)v.z; h[3] = (f16)v.w;
    *(f16x4*)(xh + i) = h;
}

// 32 blocks x 768 threads (12 waves, 3/SIMD). Waves 0-7: layer-1 step i.
// Waves 8-11: layer-2 step i-1. Ping-pong h1/h2 LDS buffers => ONE barrier
// per step; compile-time parity. OPERAND-SWAPPED vs R7: weights are the MFMA
// A operand, h/x fragments are B (fragment contents identical -- A.m and B.n
// both map to lane&15). D rows = 4 consecutive gate cols per lane =>
// packed ds_write_b64 h-writeback + bias as MFMA C-init (no epilogue adds).
__global__ __launch_bounds__(768, 3)
void lstm_pipe9(const f16* __restrict__ xh, const float* __restrict__ W1,
                const float* __restrict__ U1, const float* __restrict__ b1,
                const float* __restrict__ W2, const float* __restrict__ U2,
                const float* __restrict__ b2, const float* __restrict__ Wd1,
                const float* __restrict__ bd1,const float* __restrict__ Wd2,
                const float* __restrict__ bd2, float* __restrict__ out)
{
    const int tid  = threadIdx.x;
    const int w    = tid >> 6;      // wave 0..11
    const int lane = tid & 63;
    const int quad = lane >> 4;     // 0..3
    const int lid  = lane & 15;     // 0..15
    const int b0   = blockIdx.x * 16;
    const bool isL1 = (w < 8);
    const int  j    = isL1 ? w : (w - 8);

    __shared__ __align__(16) f16 h1b[2][16][S1];
    __shared__ __align__(16) f16 h2b[2][16][S2];
    // x chunk layout: [tl(8)][fseg(8)][row(16)] of 8-f16 (16 B) segments.
    __shared__ __align__(16) f16 xlds[2][XC * 8 * 16 * 8];
    __shared__ float h2f[16][H2];
    __shared__ float dsh[16][D1];

    for (int i = tid; i < 2 * 16 * S1 / 2; i += 768) ((unsigned*)h1b)[i] = 0u;
    for (int i = tid; i < 2 * 16 * S2 / 2; i += 768) ((unsigned*)h2b)[i] = 0u;

    // stage x chunk 0 (timesteps 0..7) into xlds[0]
    for (int s = tid; s < XC * 8 * 16; s += 768) {
        const int tl = s >> 7, fs = (s >> 4) & 7, row = s & 15;
        const f16* gp = xh + ((size_t)(b0 + row) * TT + tl) * FF + fs * 8;
        gl_lds16(gp, &xlds[0][(s >> 6) * 512]);
    }

    // ---- weight fragments wt[g][c] (A operand): lane holds col n = base+lid,
    // rows k = 32c + quad*8 + e. Identical values to R7's B fragments.
    // gates 0,1,3 (i,f,o) pre-scaled by log2e; gate 2 (candidate, relu) raw.
    // L1 (w<8):  chunks 0..3 = U1 (h1, K=128), 4..5 = W1 (x, K=64)
    // L2 (w>=8): chunks 0..3 = W2 (h1, K=128), 4..5 = U2 (h2, K=64)
    f16x8 wt[4][6];
    f32x4 bsp[4];     // bias for this lane's 4 consecutive gate cols (C-init)
    float cs[4] = {0.f, 0.f, 0.f, 0.f};

    if (isL1) {
#pragma unroll
        for (int g = 0; g < 4; ++g) {
            const float sc = (g == 2) ? 1.f : L2E;
            const int n = 128 * g + 16 * w + lid;
#pragma unroll
            for (int rr = 0; rr < 4; ++rr)
                bsp[g][rr] = b1[128 * g + 16 * w + quad * 4 + rr] * sc;
#pragma unroll
            for (int c = 0; c < 4; ++c) {
                f16x8 f;
#pragma unroll
                for (int e = 0; e < 8; ++e)
                    f[e] = (f16)(U1[(32 * c + quad * 8 + e) * 512 + n] * sc);
                wt[g][c] = f;
            }
#pragma unroll
            for (int c = 0; c < 2; ++c) {
                f16x8 f;
#pragma unroll
                for (int e = 0; e < 8; ++e)
                    f[e] = (f16)(W1[(32 * c + quad * 8 + e) * 512 + n] * sc);
                wt[g][4 + c] = f;
            }
        }
    } else {
#pragma unroll
        for (int g = 0; g < 4; ++g) {
            const float sc = (g == 2) ? 1.f : L2E;
            const int n = 64 * g + 16 * j + lid;
#pragma unroll
            for (int rr = 0; rr < 4; ++rr)
                bsp[g][rr] = b2[64 * g + 16 * j + quad * 4 + rr] * sc;
#pragma unroll
            for (int c = 0; c < 4; ++c) {
                f16x8 f;
#pragma unroll
                for (int e = 0; e < 8; ++e)
                    f[e] = (f16)(W2[(32 * c + quad * 8 + e) * 256 + n] * sc);
                wt[g][c] = f;
            }
#pragma unroll
            for (int c = 0; c < 2; ++c) {
                f16x8 f;
#pragma unroll
                for (int e = 0; e < 8; ++e)
                    f[e] = (f16)(U2[(32 * c + quad * 8 + e) * 256 + n] * sc);
                wt[g][4 + c] = f;
            }
        }
    }
    __syncthreads();   // also drains staging vmcnt

    // one pipeline step; PAR = i&1 known at compile time => LDS immediates.
    // D[m=quad*4+r][n=lid]: m = gate col local (4 consecutive), n = batch row.
    // cs[r] = cell state for (batch lid, unit base+quad*4+r).
    auto step = [&](auto parc, int i) {
        constexpr int PAR = decltype(parc)::value;
        constexpr int PR = PAR ^ 1;   // h1[i-1]
        constexpr int PW = PAR;       // h1[i]
        constexpr int QR = PAR;       // h2[i-2]
        constexpr int QW = PAR ^ 1;   // h2[i-1]
        if (isL1) {
            const f16* xc = &xlds[(i >> 3) & 1][(i & 7) * 1024];
            f16x8 fr0 = *(const f16x8*)&h1b[PR][lid][quad * 8];
            f16x8 fr1 = *(const f16x8*)&h1b[PR][lid][32 + quad * 8];
            f16x8 fr2 = *(const f16x8*)&h1b[PR][lid][64 + quad * 8];
            f16x8 fr3 = *(const f16x8*)&h1b[PR][lid][96 + quad * 8];
            f16x8 xf0 = *(const f16x8*)&xc[(quad * 16 + lid) * 8];
            f16x8 xf1 = *(const f16x8*)&xc[((4 + quad) * 16 + lid) * 8];
            f32x4 acc[4];
#pragma unroll
            for (int g = 0; g < 4; ++g) {
                f32x4 a = mfma16(wt[g][0], fr0, bsp[g]);   // weights = A operand
                a = mfma16(wt[g][1], fr1, a);
                a = mfma16(wt[g][2], fr2, a);
                a = mfma16(wt[g][3], fr3, a);
                a = mfma16(wt[g][4], xf0, a);
                a = mfma16(wt[g][5], xf1, a);
                acc[g] = a;
            }
            f16x4 hp;
#pragma unroll
            for (int r = 0; r < 4; ++r) {
                const float ig = sigm2(acc[0][r]);
                const float fg = sigm2(acc[1][r]);
                const float gg = fmaxf(acc[2][r], 0.f);
                const float og = sigm2(acc[3][r]);
                const float cc = fg * cs[r] + ig * gg;
                cs[r] = cc;
                hp[r] = (f16)(og * fmaxf(cc, 0.f));
            }
            *(f16x4*)&h1b[PW][lid][16 * w + quad * 4] = hp;   // packed b64
        } else {
            if (i >= 1) {
                f16x8 fr0 = *(const f16x8*)&h1b[PR][lid][quad * 8];
                f16x8 fr1 = *(const f16x8*)&h1b[PR][lid][32 + quad * 8];
                f16x8 fr2 = *(const f16x8*)&h1b[PR][lid][64 + quad * 8];
                f16x8 fr3 = *(const f16x8*)&h1b[PR][lid][96 + quad * 8];
                f16x8 fr4 = *(const f16x8*)&h2b[QR][lid][quad * 8];
                f16x8 fr5 = *(const f16x8*)&h2b[QR][lid][32 + quad * 8];
                f32x4 acc[4];
#pragma unroll
                for (int g = 0; g < 4; ++g) {
                    f32x4 a = mfma16(wt[g][0], fr0, bsp[g]);
                    a = mfma16(wt[g][1], fr1, a);
                    a = mfma16(wt[g][2], fr2, a);
                    a = mfma16(wt[g][3], fr3, a);
                    a = mfma16(wt[g][4], fr4, a);
                    a = mfma16(wt[g][5], fr5, a);
                    acc[g] = a;
                }
                f16x4 hp;
#pragma unroll
                for (int r = 0; r < 4; ++r) {
                    const float ig = sigm2(acc[0][r]);
                    const float fg = sigm2(acc[1][r]);
                    const float gg = fmaxf(acc[2][r], 0.f);
                    const float og = sigm2(acc[3][r]);
                    const float cc = fg * cs[r] + ig * gg;
                    cs[r] = cc;
                    hp[r] = (f16)(og * fmaxf(cc, 0.f));
                }
                *(f16x4*)&h2b[QW][lid][16 * j + quad * 4] = hp;   // packed b64
            }
        }
    };

    // ---------------- main loop, unrolled x2: ONE barrier per step ----------------
    for (int ii = 0; ii < TT; ii += 2) {
        if ((ii & (XC - 1)) == 0 && ii + XC < TT) {
            const int nc = (ii >> 3) + 1;
            f16* dst = xlds[nc & 1];
            for (int s = tid; s < XC * 8 * 16; s += 768) {
                const int tl = s >> 7, fs = (s >> 4) & 7, row = s & 15;
                const f16* gp = xh + ((size_t)(b0 + row) * TT + (nc * XC + tl)) * FF + fs * 8;
                gl_lds16(gp, &dst[(s >> 6) * 512]);
            }
        }
        step(std::integral_constant<int, 0>{}, ii);
        __syncthreads();
        step(std::integral_constant<int, 1>{}, ii + 1);
        __syncthreads();
    }

    // final pipeline step i=TT (even): L2 consumes h1[TT-1], exports h2 f32
    if (!isL1) {
        f16x8 fr0 = *(const f16x8*)&h1b[1][lid][quad * 8];
        f16x8 fr1 = *(const f16x8*)&h1b[1][lid][32 + quad * 8];
        f16x8 fr2 = *(const f16x8*)&h1b[1][lid][64 + quad * 8];
        f16x8 fr3 = *(const f16x8*)&h1b[1][lid][96 + quad * 8];
        f16x8 fr4 = *(const f16x8*)&h2b[0][lid][quad * 8];
        f16x8 fr5 = *(const f16x8*)&h2b[0][lid][32 + quad * 8];
        f32x4 acc[4];
#pragma unroll
        for (int g = 0; g < 4; ++g) {
            f32x4 a = mfma16(wt[g][0], fr0, bsp[g]);
            a = mfma16(wt[g][1], fr1, a);
            a = mfma16(wt[g][2], fr2, a);
            a = mfma16(wt[g][3], fr3, a);
            a = mfma16(wt[g][4], fr4, a);
            a = mfma16(wt[g][5], fr5, a);
            acc[g] = a;
        }
        float4 ho;
#pragma unroll
        for (int r = 0; r < 4; ++r) {
            const float ig = sigm2(acc[0][r]);
            const float fg = sigm2(acc[1][r]);
            const float gg = fmaxf(acc[2][r], 0.f);
            const float og = sigm2(acc[3][r]);
            const float cc = fg * cs[r] + ig * gg;
            (&ho.x)[r] = og * fmaxf(cc, 0.f);
        }
        *(float4*)&h2f[lid][16 * j + quad * 4] = ho;   // [batch][unit]
    }
    __syncthreads();

    // ---------------- dense head ----------------
    for (int idx = tid; idx < 16 * D1; idx += 768) {
        const int bq = idx / D1, p = idx % D1;
        float d = bd1[p];
#pragma unroll
        for (int k = 0; k < H2; ++k) d += h2f[bq][k] * Wd1[k * D1 + p];
        dsh[bq][p] = d * Wd2[p];
    }
    __syncthreads();
    if (tid < 16) {
        float o = bd2[0];
#pragma unroll
        for (int p = 0; p < D1; ++p) o += dsh[tid][p];
        out[b0 + tid] = o;
    }
}

extern "C" void kernel_launch(void* const* d_in, const int* in_sizes, int n_in,
                              void* d_out, int out_size, void* d_ws, size_t ws_size,
                              hipStream_t stream) {
    (void)in_sizes; (void)n_in; (void)out_size; (void)ws_size;
    const float* x   = (const float*)d_in[0];
    const float* W1  = (const float*)d_in[1];
    const float* U1  = (const float*)d_in[2];
    const float* b1  = (const float*)d_in[3];
    const float* W2  = (const float*)d_in[4];
    const float* U2  = (const float*)d_in[5];
    const float* b2  = (const float*)d_in[6];
    const float* Wd1 = (const float*)d_in[7];
    const float* bd1 = (const float*)d_in[8];
    const float* Wd2 = (const float*)d_in[9];
    const float* bd2 = (const float*)d_in[10];
    float* out = (float*)d_out;
    f16*   xh  = (f16*)d_ws;    // 512*512*64 f16 = 32 MiB scratch

    const int nx = 512 * 512 * 64;
    cvt_x_kernel<<<dim3(nx / (256 * 4)), dim3(256), 0, stream>>>(x, xh);
    lstm_pipe9<<<dim3(32), dim3(768), 0, stream>>>(
        xh, W1, U1, b1, W2, U2, b2, Wd1, bd1, Wd2, bd2, out);
}